// Round 2
// baseline (3240.940 us; speedup 1.0000x reference)
//
#include <hip/hip_runtime.h>
#include <hip/hip_bf16.h>

#define NB 4
#define NPTS 8192
#define CIN 32
#define COUT 64
#define MOUT 2048   // NPTS / STRIDE
#define KNN 16
#define EPSBN 1e-5f

typedef float f32x2 __attribute__((ext_vector_type(2)));

// ---------------------------------------------------------------------------
// Setup: fold BN into conv weights.  w1s[o][c] = w1[o][c]*a1[o], c1[o]=b1-m1*a1
// wbuf layout (floats): [0,2240) w1s | [2240,2304) c1 | [2304,6400) w2s | [6400,6464) c2
// ---------------------------------------------------------------------------
__global__ void setup_kernel(const float* __restrict__ w1, const float* __restrict__ g1,
                             const float* __restrict__ b1, const float* __restrict__ m1,
                             const float* __restrict__ v1, const float* __restrict__ w2,
                             const float* __restrict__ g2, const float* __restrict__ b2,
                             const float* __restrict__ m2, const float* __restrict__ v2,
                             float* __restrict__ wbuf) {
    int o = threadIdx.x;
    if (o >= 64) return;
    float a1 = g1[o] * rsqrtf(v1[o] + EPSBN);
    wbuf[2240 + o] = b1[o] - m1[o] * a1;
    for (int c = 0; c < 35; ++c) wbuf[o * 35 + c] = w1[o * 35 + c] * a1;
    float a2 = g2[o] * rsqrtf(v2[o] + EPSBN);
    wbuf[6400 + o] = b2[o] - m2[o] * a2;
    for (int c = 0; c < 64; ++c) wbuf[2304 + o * 64 + c] = w2[o * 64 + c] * a2;
}

// ---------------------------------------------------------------------------
// Transpose x (B,C,N) -> xt (B,N,C) with LDS tiles (coalesced both sides)
// ---------------------------------------------------------------------------
__global__ __launch_bounds__(256) void transpose_kernel(const float* __restrict__ x,
                                                        float* __restrict__ xt) {
    __shared__ float tile[CIN][65];
    int b = blockIdx.y;
    int n0 = blockIdx.x * 64;
    int tid = threadIdx.x;
#pragma unroll
    for (int r = 0; r < 8; ++r) {
        int i = r * 256 + tid;
        int c = i >> 6, n = i & 63;
        tile[c][n] = x[((size_t)b * CIN + c) * NPTS + n0 + n];
    }
    __syncthreads();
#pragma unroll
    for (int r = 0; r < 8; ++r) {
        int i = r * 256 + tid;
        int n = i >> 5, c = i & 31;
        xt[((size_t)b * NPTS + n0 + n) * CIN + c] = tile[c][n];
    }
}

// ---------------------------------------------------------------------------
// FPS v2: one block per batch, 1024 threads, 8 points/thread in REGISTERS
// (32 VGPRs of arrays -> no spill; __launch_bounds__(1024,4) allows 128).
// Packed f32x2 math (exact: fp contract off). Cross-wave argmax via one
// packed-u64 LDS atomicMax per wave; ONE barrier/iter with mod-4 slots.
// Exactness: d = (dx*dx + dy*dy) + dz*dz, no contraction; argmax first-max
// (strict >, tie -> smaller index via ~idx in packed low word).
// ---------------------------------------------------------------------------
#define FPS_PT 8
__global__ __launch_bounds__(1024, 4) void fps_kernel(const float* __restrict__ p1,
                                                      float* __restrict__ p2out) {
#pragma clang fp contract(off)
    int b = blockIdx.x;
    int tid = threadIdx.x;
    int lane = tid & 63;
    const float* P = p1 + (size_t)b * NPTS * 3;

    f32x2 px[4], py[4], pz[4], dmin[4];
    int base = tid * FPS_PT;
#pragma unroll
    for (int s = 0; s < 4; ++s) {
        int j = base + 2 * s;
        px[s] = (f32x2){P[j * 3 + 0], P[j * 3 + 3]};
        py[s] = (f32x2){P[j * 3 + 1], P[j * 3 + 4]};
        pz[s] = (f32x2){P[j * 3 + 2], P[j * 3 + 5]};
        dmin[s] = (f32x2){1e10f, 1e10f};
    }

    __shared__ unsigned long long slot[4];
    if (tid < 4) slot[tid] = 0ull;

    float lx = P[0], ly = P[1], lz = P[2];
    if (tid == 0) {
        p2out[(size_t)(b * MOUT) * 3 + 0] = lx;
        p2out[(size_t)(b * MOUT) * 3 + 1] = ly;
        p2out[(size_t)(b * MOUT) * 3 + 2] = lz;
    }
    __syncthreads();

    for (int m = 1; m < MOUT; ++m) {
        // ---- phase A: update dmin, local argmax over 8 pts ----
        f32x2 lx2 = {lx, lx}, ly2 = {ly, ly}, lz2 = {lz, lz};
        float bv = -1.0f;
        int bi = 0;
#pragma unroll
        for (int s = 0; s < 4; ++s) {
            f32x2 dx = px[s] - lx2;
            f32x2 dy = py[s] - ly2;
            f32x2 dz = pz[s] - lz2;
            f32x2 d = (dx * dx + dy * dy) + dz * dz;   // contract OFF: mul/add only
            f32x2 nd = __builtin_elementwise_min(dmin[s], d);
            dmin[s] = nd;
            if (nd.x > bv) { bv = nd.x; bi = base + 2 * s; }
            if (nd.y > bv) { bv = nd.y; bi = base + 2 * s + 1; }
        }
        // ---- wave butterfly argmax, ties -> smaller index ----
#pragma unroll
        for (int off = 32; off >= 1; off >>= 1) {
            float ov = __shfl_xor(bv, off);
            int   oi = __shfl_xor(bi, off);
            if (ov > bv || (ov == bv && oi < bi)) { bv = ov; bi = oi; }
        }
        // ---- cross-wave: packed u64 atomic max (dist bits | ~idx) ----
        if (lane == 0) {
            unsigned long long pk =
                ((unsigned long long)__float_as_uint(bv) << 32) |
                (unsigned long long)(unsigned)(~bi);
            atomicMax(&slot[m & 3], pk);
        }
        if (tid == 0) slot[(m + 2) & 3] = 0ull;   // 2 barriers away from readers
        __syncthreads();
        unsigned long long w = slot[m & 3];
        int widx = __builtin_amdgcn_readfirstlane(~(unsigned)(w & 0xffffffffu));
        lx = P[widx * 3 + 0];
        ly = P[widx * 3 + 1];
        lz = P[widx * 3 + 2];
        if (tid == 0) {
            p2out[((size_t)b * MOUT + m) * 3 + 0] = lx;
            p2out[((size_t)b * MOUT + m) * 3 + 1] = ly;
            p2out[((size_t)b * MOUT + m) * 3 + 2] = lz;
        }
    }
}

// ---------------------------------------------------------------------------
// kNN: one wave per query. Distributed sorted top-16 in lanes 0..15,
// ballot-compacted insertion (no per-lane divergent insertion sort).
// d2 mirrors reference formula: (s2[m]+s1[n]) - 2*dot  (no contraction).
// ---------------------------------------------------------------------------
__global__ __launch_bounds__(256) void knn_kernel(const float* __restrict__ p1,
                                                  const float* __restrict__ p2,
                                                  int* __restrict__ nnout) {
    int tid = threadIdx.x;
    int lane = tid & 63, wid = tid >> 6;
    int qid = blockIdx.x * 4 + wid;          // 0..8191
    int b = qid >> 11;
    const float* Pb = p1 + (size_t)b * NPTS * 3;
    const float* q = p2 + (size_t)qid * 3;
    float qx = q[0], qy = q[1], qz = q[2];
    float s2q = __fadd_rn(__fadd_rn(__fmul_rn(qx, qx), __fmul_rn(qy, qy)),
                          __fmul_rn(qz, qz));

    float tval = 3.0e38f;   // distributed sorted list (lanes 0..15)
    int   tidx = -1;
    float tau = 3.0e38f;

    for (int n0 = 0; n0 < NPTS; n0 += 64) {
        int n = n0 + lane;
        const float* pp = Pb + n * 3;
        float px = pp[0], py = pp[1], pz = pp[2];
        float s1n = __fadd_rn(__fadd_rn(__fmul_rn(px, px), __fmul_rn(py, py)),
                              __fmul_rn(pz, pz));
        float dot = __fadd_rn(__fadd_rn(__fmul_rn(qx, px), __fmul_rn(qy, py)),
                              __fmul_rn(qz, pz));
        float d2 = __fsub_rn(__fadd_rn(s2q, s1n), __fmul_rn(2.0f, dot));

        unsigned long long act = __ballot(d2 < tau);
        while (act) {
            int l = __ffsll(act) - 1;
            float dd = __shfl(d2, l);
            int   nn_ = __shfl(n, l);
            unsigned long long mle = __ballot(lane < 16 && tval <= dd);
            int pos = __popcll(mle);                 // stable insert position
            float sv = __shfl_up(tval, 1);
            int   si = __shfl_up(tidx, 1);
            if (lane < 16) {
                if (lane == pos)      { tval = dd; tidx = nn_; }
                else if (lane > pos)  { tval = sv; tidx = si; }
            }
            tau = __shfl(tval, 15);
            act &= (act - 1);
            act &= __ballot(d2 < tau);
        }
    }
    if (lane < 16) nnout[(size_t)qid * KNN + lane] = tidx;
}

// ---------------------------------------------------------------------------
// Fused gather + conv1(BN-folded)+ReLU + conv2(BN-folded)+ReLU + max over K.
// Lane = (query-in-wave qq, neighbor k). Weights via uniform scalar loads.
// ---------------------------------------------------------------------------
template <int XT>
__global__ __launch_bounds__(256) void conv_kernel(const float* __restrict__ p1,
                                                   const float* __restrict__ p2,
                                                   const float* __restrict__ xsrc,
                                                   const int* __restrict__ nn,
                                                   const float* __restrict__ wbuf,
                                                   float* __restrict__ y) {
    const float* w1s = wbuf;
    const float* c1s = wbuf + 2240;
    const float* w2s = wbuf + 2304;
    const float* c2s = wbuf + 6400;
    int tid = threadIdx.x;
    int lane = tid & 63, wid = tid >> 6;
    int qq = lane >> 4, k = lane & 15;
    int qid = (blockIdx.x * 4 + wid) * 4 + qq;   // 0..8191
    int b = qid >> 11, m = qid & 2047;
    int nk = nn[(size_t)qid * KNN + k];

    const float* qp = p2 + (size_t)qid * 3;
    const float* np = p1 + ((size_t)b * NPTS + nk) * 3;
    float h[35];
    h[0] = np[0] - qp[0];
    h[1] = np[1] - qp[1];
    h[2] = np[2] - qp[2];
    if (XT) {
        const float4* xr = (const float4*)(xsrc + ((size_t)b * NPTS + nk) * CIN);
#pragma unroll
        for (int q8 = 0; q8 < 8; ++q8) {
            float4 f = xr[q8];
            h[3 + q8 * 4 + 0] = f.x;
            h[3 + q8 * 4 + 1] = f.y;
            h[3 + q8 * 4 + 2] = f.z;
            h[3 + q8 * 4 + 3] = f.w;
        }
    } else {
#pragma unroll
        for (int c = 0; c < CIN; ++c)
            h[3 + c] = xsrc[((size_t)b * CIN + c) * NPTS + nk];
    }

    float acc2[64];
#pragma unroll
    for (int o2 = 0; o2 < 64; ++o2) acc2[o2] = c2s[o2];

    for (int o = 0; o < 64; ++o) {            // dynamic loop: t1 streamed as scalar
        float a = c1s[o];
#pragma unroll
        for (int c = 0; c < 35; ++c) a = fmaf(h[c], w1s[o * 35 + c], a);
        a = fmaxf(a, 0.0f);
#pragma unroll
        for (int o2 = 0; o2 < 64; ++o2) acc2[o2] = fmaf(a, w2s[o2 * 64 + o], acc2[o2]);
    }

#pragma unroll
    for (int o2 = 0; o2 < 64; ++o2) {
        float v = fmaxf(acc2[o2], 0.0f);
        v = fmaxf(v, __shfl_xor(v, 8));
        v = fmaxf(v, __shfl_xor(v, 4));
        v = fmaxf(v, __shfl_xor(v, 2));
        v = fmaxf(v, __shfl_xor(v, 1));
        if ((lane & 15) == (o2 & 15))
            y[((size_t)b * COUT + o2) * MOUT + m] = v;
    }
}

// ---------------------------------------------------------------------------
extern "C" void kernel_launch(void* const* d_in, const int* in_sizes, int n_in,
                              void* d_out, int out_size, void* d_ws, size_t ws_size,
                              hipStream_t stream) {
    const float* p1 = (const float*)d_in[0];
    const float* x  = (const float*)d_in[1];
    const float* w1 = (const float*)d_in[2];
    const float* g1 = (const float*)d_in[3];
    const float* b1 = (const float*)d_in[4];
    const float* m1 = (const float*)d_in[5];
    const float* v1 = (const float*)d_in[6];
    const float* w2 = (const float*)d_in[7];
    const float* g2 = (const float*)d_in[8];
    const float* b2 = (const float*)d_in[9];
    const float* m2 = (const float*)d_in[10];
    const float* v2 = (const float*)d_in[11];

    float* p2o = (float*)d_out;                       // (B,M,3)
    float* yo  = p2o + (size_t)NB * MOUT * 3;         // (B,COUT,M)

    char* ws = (char*)d_ws;
    int*   nn   = (int*)ws;                            // 512 KiB
    float* wbuf = (float*)(ws + 512 * 1024);           // 25.9 KiB
    float* xt   = (float*)(ws + 1024 * 1024);          // 4 MiB
    bool use_xt = ws_size >= (size_t)(1024 * 1024) + (size_t)NB * NPTS * CIN * 4;

    setup_kernel<<<1, 64, 0, stream>>>(w1, g1, b1, m1, v1, w2, g2, b2, m2, v2, wbuf);
    if (use_xt)
        transpose_kernel<<<dim3(NPTS / 64, NB), 256, 0, stream>>>(x, xt);
    fps_kernel<<<NB, 1024, 0, stream>>>(p1, p2o);
    knn_kernel<<<(NB * MOUT) / 4, 256, 0, stream>>>(p1, p2o, nn);
    if (use_xt)
        conv_kernel<1><<<(NB * MOUT) / 16, 256, 0, stream>>>(p1, p2o, xt, nn, wbuf, yo);
    else
        conv_kernel<0><<<(NB * MOUT) / 16, 256, 0, stream>>>(p1, p2o, x, nn, wbuf, yo);
}

// Round 3
// 3104.321 us; speedup vs baseline: 1.0440x; 1.0440x over previous
//
#include <hip/hip_runtime.h>
#include <hip/hip_bf16.h>

#define NB 4
#define NPTS 8192
#define CIN 32
#define COUT 64
#define MOUT 2048   // NPTS / STRIDE
#define KNN 16
#define EPSBN 1e-5f

// ---------------------------------------------------------------------------
// Setup: fold BN into conv weights.  w1s[o][c] = w1[o][c]*a1[o], c1[o]=b1-m1*a1
// wbuf layout (floats): [0,2240) w1s | [2240,2304) c1 | [2304,6400) w2s | [6400,6464) c2
// ---------------------------------------------------------------------------
__global__ void setup_kernel(const float* __restrict__ w1, const float* __restrict__ g1,
                             const float* __restrict__ b1, const float* __restrict__ m1,
                             const float* __restrict__ v1, const float* __restrict__ w2,
                             const float* __restrict__ g2, const float* __restrict__ b2,
                             const float* __restrict__ m2, const float* __restrict__ v2,
                             float* __restrict__ wbuf) {
    int o = threadIdx.x;
    if (o >= 64) return;
    float a1 = g1[o] * rsqrtf(v1[o] + EPSBN);
    wbuf[2240 + o] = b1[o] - m1[o] * a1;
    for (int c = 0; c < 35; ++c) wbuf[o * 35 + c] = w1[o * 35 + c] * a1;
    float a2 = g2[o] * rsqrtf(v2[o] + EPSBN);
    wbuf[6400 + o] = b2[o] - m2[o] * a2;
    for (int c = 0; c < 64; ++c) wbuf[2304 + o * 64 + c] = w2[o * 64 + c] * a2;
}

// ---------------------------------------------------------------------------
// Transpose x (B,C,N) -> xt (B,N,C) with LDS tiles (coalesced both sides)
// ---------------------------------------------------------------------------
__global__ __launch_bounds__(256) void transpose_kernel(const float* __restrict__ x,
                                                        float* __restrict__ xt) {
    __shared__ float tile[CIN][65];
    int b = blockIdx.y;
    int n0 = blockIdx.x * 64;
    int tid = threadIdx.x;
#pragma unroll
    for (int r = 0; r < 8; ++r) {
        int i = r * 256 + tid;
        int c = i >> 6, n = i & 63;
        tile[c][n] = x[((size_t)b * CIN + c) * NPTS + n0 + n];
    }
    __syncthreads();
#pragma unroll
    for (int r = 0; r < 8; ++r) {
        int i = r * 256 + tid;
        int n = i >> 5, c = i & 31;
        xt[((size_t)b * NPTS + n0 + n) * CIN + c] = tile[c][n];
    }
}

// ---------------------------------------------------------------------------
// FPS v3: one block per batch, 1024 threads, 8 points/thread in registers,
// PINNED via empty asm (defeats the remat/sink that produced VGPR=28 in v2).
// All points also staged in LDS (96 KB) so the winner-coordinate fetch on the
// serial chain is an LDS broadcast, not an L2 load.
// Exactness: d = (dx*dx + dy*dy) + dz*dz via __f*_rn (no contraction);
// argmax = first occurrence of max (strict >, cross-wave tie via ~idx pack).
// ---------------------------------------------------------------------------
#define FPS_PT 8
__global__ __launch_bounds__(1024, 4) void fps_kernel(const float* __restrict__ p1,
                                                      float* __restrict__ p2out) {
    int b = blockIdx.x;
    int tid = threadIdx.x;
    int lane = tid & 63;
    const float* P = p1 + (size_t)b * NPTS * 3;

    __shared__ float lp[NPTS * 3];            // 96 KiB point stage
    __shared__ unsigned long long slot[4];

    // stage all points: 6144 float4 loads, 6 per thread, coalesced
    const float4* P4 = (const float4*)P;
    float4* L4 = (float4*)lp;
#pragma unroll
    for (int r = 0; r < 6; ++r) {
        int i = r * 1024 + tid;
        L4[i] = P4[i];
    }
    if (tid < 4) slot[tid] = 0ull;
    __syncthreads();

    float px[FPS_PT], py[FPS_PT], pz[FPS_PT], dmin[FPS_PT];
    int base = tid * FPS_PT;
#pragma unroll
    for (int s = 0; s < FPS_PT; ++s) {
        int j = (base + s) * 3;
        px[s] = lp[j + 0];
        py[s] = lp[j + 1];
        pz[s] = lp[j + 2];
        dmin[s] = 1e10f;
        // pin: opaque producer -> compiler cannot re-load these inside the loop
        asm volatile("" : "+v"(px[s]), "+v"(py[s]), "+v"(pz[s]));
    }

    float lx = lp[0], ly = lp[1], lz = lp[2];
    if (tid == 0) {
        p2out[(size_t)(b * MOUT) * 3 + 0] = lx;
        p2out[(size_t)(b * MOUT) * 3 + 1] = ly;
        p2out[(size_t)(b * MOUT) * 3 + 2] = lz;
    }

    for (int m = 1; m < MOUT; ++m) {
        // ---- phase A: update dmin, local argmax over 8 pts ----
        float bv, dx, dy, dz, d, nd;
        int bi = base;
        dx = __fsub_rn(px[0], lx);
        dy = __fsub_rn(py[0], ly);
        dz = __fsub_rn(pz[0], lz);
        d = __fadd_rn(__fadd_rn(__fmul_rn(dx, dx), __fmul_rn(dy, dy)), __fmul_rn(dz, dz));
        nd = fminf(dmin[0], d);
        dmin[0] = nd;
        bv = nd;
#pragma unroll
        for (int s = 1; s < FPS_PT; ++s) {
            dx = __fsub_rn(px[s], lx);
            dy = __fsub_rn(py[s], ly);
            dz = __fsub_rn(pz[s], lz);
            d = __fadd_rn(__fadd_rn(__fmul_rn(dx, dx), __fmul_rn(dy, dy)),
                          __fmul_rn(dz, dz));
            nd = fminf(dmin[s], d);
            dmin[s] = nd;
            if (nd > bv) { bv = nd; bi = base + s; }   // strict > : first max
        }
        // ---- wave butterfly argmax, ties -> smaller index ----
#pragma unroll
        for (int off = 32; off >= 1; off >>= 1) {
            float ov = __shfl_xor(bv, off);
            int   oi = __shfl_xor(bi, off);
            if (ov > bv || (ov == bv && oi < bi)) { bv = ov; bi = oi; }
        }
        // ---- cross-wave: packed u64 atomic max (dist bits | ~idx) ----
        if (lane == 0) {
            unsigned long long pk =
                ((unsigned long long)__float_as_uint(bv) << 32) |
                (unsigned long long)(unsigned)(~bi);
            atomicMax(&slot[m & 3], pk);
        }
        if (tid == 0) slot[(m + 2) & 3] = 0ull;   // 2 barriers away from readers
        __syncthreads();
        unsigned long long w = slot[m & 3];
        int widx = __builtin_amdgcn_readfirstlane(~(unsigned)(w & 0xffffffffu));
        int wj = widx * 3;
        lx = lp[wj + 0];
        ly = lp[wj + 1];
        lz = lp[wj + 2];
        if (tid == 0) {
            p2out[((size_t)b * MOUT + m) * 3 + 0] = lx;
            p2out[((size_t)b * MOUT + m) * 3 + 1] = ly;
            p2out[((size_t)b * MOUT + m) * 3 + 2] = lz;
        }
    }
}

// ---------------------------------------------------------------------------
// kNN: one wave per query. Distributed sorted top-16 in lanes 0..15,
// ballot-compacted insertion (no per-lane divergent insertion sort).
// d2 mirrors reference formula: (s2[m]+s1[n]) - 2*dot  (no contraction).
// ---------------------------------------------------------------------------
__global__ __launch_bounds__(256) void knn_kernel(const float* __restrict__ p1,
                                                  const float* __restrict__ p2,
                                                  int* __restrict__ nnout) {
    int tid = threadIdx.x;
    int lane = tid & 63, wid = tid >> 6;
    int qid = blockIdx.x * 4 + wid;          // 0..8191
    int b = qid >> 11;
    const float* Pb = p1 + (size_t)b * NPTS * 3;
    const float* q = p2 + (size_t)qid * 3;
    float qx = q[0], qy = q[1], qz = q[2];
    float s2q = __fadd_rn(__fadd_rn(__fmul_rn(qx, qx), __fmul_rn(qy, qy)),
                          __fmul_rn(qz, qz));

    float tval = 3.0e38f;   // distributed sorted list (lanes 0..15)
    int   tidx = -1;
    float tau = 3.0e38f;

    for (int n0 = 0; n0 < NPTS; n0 += 64) {
        int n = n0 + lane;
        const float* pp = Pb + n * 3;
        float px = pp[0], py = pp[1], pz = pp[2];
        float s1n = __fadd_rn(__fadd_rn(__fmul_rn(px, px), __fmul_rn(py, py)),
                              __fmul_rn(pz, pz));
        float dot = __fadd_rn(__fadd_rn(__fmul_rn(qx, px), __fmul_rn(qy, py)),
                              __fmul_rn(qz, pz));
        float d2 = __fsub_rn(__fadd_rn(s2q, s1n), __fmul_rn(2.0f, dot));

        unsigned long long act = __ballot(d2 < tau);
        while (act) {
            int l = __ffsll(act) - 1;
            float dd = __shfl(d2, l);
            int   nn_ = __shfl(n, l);
            unsigned long long mle = __ballot(lane < 16 && tval <= dd);
            int pos = __popcll(mle);                 // stable insert position
            float sv = __shfl_up(tval, 1);
            int   si = __shfl_up(tidx, 1);
            if (lane < 16) {
                if (lane == pos)      { tval = dd; tidx = nn_; }
                else if (lane > pos)  { tval = sv; tidx = si; }
            }
            tau = __shfl(tval, 15);
            act &= (act - 1);
            act &= __ballot(d2 < tau);
        }
    }
    if (lane < 16) nnout[(size_t)qid * KNN + lane] = tidx;
}

// ---------------------------------------------------------------------------
// Fused gather + conv1(BN-folded)+ReLU + conv2(BN-folded)+ReLU + max over K.
// Lane = (query-in-wave qq, neighbor k). Weights via uniform scalar loads.
// ---------------------------------------------------------------------------
template <int XT>
__global__ __launch_bounds__(256) void conv_kernel(const float* __restrict__ p1,
                                                   const float* __restrict__ p2,
                                                   const float* __restrict__ xsrc,
                                                   const int* __restrict__ nn,
                                                   const float* __restrict__ wbuf,
                                                   float* __restrict__ y) {
    const float* w1s = wbuf;
    const float* c1s = wbuf + 2240;
    const float* w2s = wbuf + 2304;
    const float* c2s = wbuf + 6400;
    int tid = threadIdx.x;
    int lane = tid & 63, wid = tid >> 6;
    int qq = lane >> 4, k = lane & 15;
    int qid = (blockIdx.x * 4 + wid) * 4 + qq;   // 0..8191
    int b = qid >> 11, m = qid & 2047;
    int nk = nn[(size_t)qid * KNN + k];

    const float* qp = p2 + (size_t)qid * 3;
    const float* np = p1 + ((size_t)b * NPTS + nk) * 3;
    float h[35];
    h[0] = np[0] - qp[0];
    h[1] = np[1] - qp[1];
    h[2] = np[2] - qp[2];
    if (XT) {
        const float4* xr = (const float4*)(xsrc + ((size_t)b * NPTS + nk) * CIN);
#pragma unroll
        for (int q8 = 0; q8 < 8; ++q8) {
            float4 f = xr[q8];
            h[3 + q8 * 4 + 0] = f.x;
            h[3 + q8 * 4 + 1] = f.y;
            h[3 + q8 * 4 + 2] = f.z;
            h[3 + q8 * 4 + 3] = f.w;
        }
    } else {
#pragma unroll
        for (int c = 0; c < CIN; ++c)
            h[3 + c] = xsrc[((size_t)b * CIN + c) * NPTS + nk];
    }

    float acc2[64];
#pragma unroll
    for (int o2 = 0; o2 < 64; ++o2) acc2[o2] = c2s[o2];

    for (int o = 0; o < 64; ++o) {            // dynamic loop: t1 streamed as scalar
        float a = c1s[o];
#pragma unroll
        for (int c = 0; c < 35; ++c) a = fmaf(h[c], w1s[o * 35 + c], a);
        a = fmaxf(a, 0.0f);
#pragma unroll
        for (int o2 = 0; o2 < 64; ++o2) acc2[o2] = fmaf(a, w2s[o2 * 64 + o], acc2[o2]);
    }

#pragma unroll
    for (int o2 = 0; o2 < 64; ++o2) {
        float v = fmaxf(acc2[o2], 0.0f);
        v = fmaxf(v, __shfl_xor(v, 8));
        v = fmaxf(v, __shfl_xor(v, 4));
        v = fmaxf(v, __shfl_xor(v, 2));
        v = fmaxf(v, __shfl_xor(v, 1));
        if ((lane & 15) == (o2 & 15))
            y[((size_t)b * COUT + o2) * MOUT + m] = v;
    }
}

// ---------------------------------------------------------------------------
extern "C" void kernel_launch(void* const* d_in, const int* in_sizes, int n_in,
                              void* d_out, int out_size, void* d_ws, size_t ws_size,
                              hipStream_t stream) {
    const float* p1 = (const float*)d_in[0];
    const float* x  = (const float*)d_in[1];
    const float* w1 = (const float*)d_in[2];
    const float* g1 = (const float*)d_in[3];
    const float* b1 = (const float*)d_in[4];
    const float* m1 = (const float*)d_in[5];
    const float* v1 = (const float*)d_in[6];
    const float* w2 = (const float*)d_in[7];
    const float* g2 = (const float*)d_in[8];
    const float* b2 = (const float*)d_in[9];
    const float* m2 = (const float*)d_in[10];
    const float* v2 = (const float*)d_in[11];

    float* p2o = (float*)d_out;                       // (B,M,3)
    float* yo  = p2o + (size_t)NB * MOUT * 3;         // (B,COUT,M)

    char* ws = (char*)d_ws;
    int*   nn   = (int*)ws;                            // 512 KiB
    float* wbuf = (float*)(ws + 512 * 1024);           // 25.9 KiB
    float* xt   = (float*)(ws + 1024 * 1024);          // 4 MiB
    bool use_xt = ws_size >= (size_t)(1024 * 1024) + (size_t)NB * NPTS * CIN * 4;

    setup_kernel<<<1, 64, 0, stream>>>(w1, g1, b1, m1, v1, w2, g2, b2, m2, v2, wbuf);
    if (use_xt)
        transpose_kernel<<<dim3(NPTS / 64, NB), 256, 0, stream>>>(x, xt);
    fps_kernel<<<NB, 1024, 0, stream>>>(p1, p2o);
    knn_kernel<<<(NB * MOUT) / 4, 256, 0, stream>>>(p1, p2o, nn);
    if (use_xt)
        conv_kernel<1><<<(NB * MOUT) / 16, 256, 0, stream>>>(p1, p2o, xt, nn, wbuf, yo);
    else
        conv_kernel<0><<<(NB * MOUT) / 16, 256, 0, stream>>>(p1, p2o, x, nn, wbuf, yo);
}

// Round 5
// 2578.561 us; speedup vs baseline: 1.2569x; 1.2039x over previous
//
#include <hip/hip_runtime.h>
#include <hip/hip_bf16.h>

#define NB 4
#define NPTS 8192
#define CIN 32
#define COUT 64
#define MOUT 2048   // NPTS / STRIDE
#define KNN 16
#define EPSBN 1e-5f

typedef float f32x2 __attribute__((ext_vector_type(2)));

// ---------------------------------------------------------------------------
// Packed f32 helpers (gfx90a+/gfx950 full-rate packed fp32). Inline asm keeps
// them opaque: no contraction, no reassociation -> bit-exact vs XLA mul/add.
// ---------------------------------------------------------------------------
__device__ inline f32x2 pk_add(f32x2 a, f32x2 b) {
    f32x2 r;
    asm("v_pk_add_f32 %0, %1, %2" : "=v"(r) : "v"(a), "v"(b));
    return r;
}
__device__ inline f32x2 pk_mul(f32x2 a, f32x2 b) {
    f32x2 r;
    asm("v_pk_mul_f32 %0, %1, %2" : "=v"(r) : "v"(a), "v"(b));
    return r;
}

// ---------------------------------------------------------------------------
// Setup: fold BN into conv weights.  w1s[o][c] = w1[o][c]*a1[o], c1[o]=b1-m1*a1
// wbuf layout (floats): [0,2240) w1s | [2240,2304) c1 | [2304,6400) w2s | [6400,6464) c2
// ---------------------------------------------------------------------------
__global__ void setup_kernel(const float* __restrict__ w1, const float* __restrict__ g1,
                             const float* __restrict__ b1, const float* __restrict__ m1,
                             const float* __restrict__ v1, const float* __restrict__ w2,
                             const float* __restrict__ g2, const float* __restrict__ b2,
                             const float* __restrict__ m2, const float* __restrict__ v2,
                             float* __restrict__ wbuf) {
    int o = threadIdx.x;
    if (o >= 64) return;
    float a1 = g1[o] * rsqrtf(v1[o] + EPSBN);
    wbuf[2240 + o] = b1[o] - m1[o] * a1;
    for (int c = 0; c < 35; ++c) wbuf[o * 35 + c] = w1[o * 35 + c] * a1;
    float a2 = g2[o] * rsqrtf(v2[o] + EPSBN);
    wbuf[6400 + o] = b2[o] - m2[o] * a2;
    for (int c = 0; c < 64; ++c) wbuf[2304 + o * 64 + c] = w2[o * 64 + c] * a2;
}

// ---------------------------------------------------------------------------
// Transpose x (B,C,N) -> xt (B,N,C) with LDS tiles (coalesced both sides)
// ---------------------------------------------------------------------------
__global__ __launch_bounds__(256) void transpose_kernel(const float* __restrict__ x,
                                                        float* __restrict__ xt) {
    __shared__ float tile[CIN][65];
    int b = blockIdx.y;
    int n0 = blockIdx.x * 64;
    int tid = threadIdx.x;
#pragma unroll
    for (int r = 0; r < 8; ++r) {
        int i = r * 256 + tid;
        int c = i >> 6, n = i & 63;
        tile[c][n] = x[((size_t)b * CIN + c) * NPTS + n0 + n];
    }
    __syncthreads();
#pragma unroll
    for (int r = 0; r < 8; ++r) {
        int i = r * 256 + tid;
        int n = i >> 5, c = i & 31;
        xt[((size_t)b * NPTS + n0 + n) * CIN + c] = tile[c][n];
    }
}

// ---------------------------------------------------------------------------
// FPS v4: 1024 threads/block, 8 pts/thread in registers (pinned), points
// staged in LDS. Phase A uses packed-f32 asm (half the issue slots). Argmax
// is value-only: DPP row_shr max (4) + xor16 swizzle + xor32 shuffle, then
// index recovery by bit-equality scan (first occurrence of max = jnp.argmax:
// lane-major layout, descending slot scan, ballot -> lowest lane, ~idx pack
// for cross-wave tie -> smallest index). Distances >= 0 so bit== is float==.
// ---------------------------------------------------------------------------
#define FPS_PT 8
__global__ __launch_bounds__(1024, 4) void fps_kernel(const float* __restrict__ p1,
                                                      float* __restrict__ p2out) {
    int b = blockIdx.x;
    int tid = threadIdx.x;
    int lane = tid & 63;
    const float* P = p1 + (size_t)b * NPTS * 3;

    __shared__ float lp[NPTS * 3];            // 96 KiB point stage
    __shared__ unsigned long long slot[4];

    const float4* P4 = (const float4*)P;
    float4* L4 = (float4*)lp;
#pragma unroll
    for (int r = 0; r < 6; ++r) {
        int i = r * 1024 + tid;
        L4[i] = P4[i];
    }
    if (tid < 4) slot[tid] = 0ull;
    __syncthreads();

    f32x2 px[4], py[4], pz[4], dmin[4];
    int base = tid * FPS_PT;
#pragma unroll
    for (int s = 0; s < 4; ++s) {
        int j = (base + 2 * s) * 3;
        px[s] = (f32x2){lp[j + 0], lp[j + 3]};
        py[s] = (f32x2){lp[j + 1], lp[j + 4]};
        pz[s] = (f32x2){lp[j + 2], lp[j + 5]};
        dmin[s] = (f32x2){1e10f, 1e10f};
        asm volatile("" : "+v"(px[s]), "+v"(py[s]), "+v"(pz[s]));
    }

    float lx = lp[0], ly = lp[1], lz = lp[2];
    if (tid == 0) {
        p2out[(size_t)(b * MOUT) * 3 + 0] = lx;
        p2out[(size_t)(b * MOUT) * 3 + 1] = ly;
        p2out[(size_t)(b * MOUT) * 3 + 2] = lz;
    }

    for (int m = 1; m < MOUT; ++m) {
        // ---- phase A: packed distance + dmin update + value-max ----
        float nlx = -lx, nly = -ly, nlz = -lz;
        f32x2 cx = {nlx, nlx}, cy = {nly, nly}, cz = {nlz, nlz};
        float bv;
        {
            float t[8];
#pragma unroll
            for (int s = 0; s < 4; ++s) {
                f32x2 dx = pk_add(px[s], cx);          // p - l, exact
                f32x2 dy = pk_add(py[s], cy);
                f32x2 dz = pk_add(pz[s], cz);
                f32x2 xx = pk_mul(dx, dx);
                f32x2 yy = pk_mul(dy, dy);
                f32x2 zz = pk_mul(dz, dz);
                f32x2 d = pk_add(pk_add(xx, yy), zz);  // (dx2+dy2)+dz2
                float n0 = fminf(dmin[s].x, d.x);
                float n1 = fminf(dmin[s].y, d.y);
                dmin[s].x = n0;
                dmin[s].y = n1;
                t[2 * s] = n0;
                t[2 * s + 1] = n1;
            }
            bv = fmaxf(fmaxf(fmaxf(t[0], t[1]), fmaxf(t[2], t[3])),
                       fmaxf(fmaxf(t[4], t[5]), fmaxf(t[6], t[7])));
        }
        // ---- wave value-max: 4x DPP row_shr + xor16 swizzle + xor32 ----
        float x0 = bv;
        {
            int xi, sh;
            xi = __float_as_int(x0);
            sh = __builtin_amdgcn_update_dpp(xi, xi, 0x111, 0xF, 0xF, false);
            x0 = fmaxf(x0, __int_as_float(sh));
            xi = __float_as_int(x0);
            sh = __builtin_amdgcn_update_dpp(xi, xi, 0x112, 0xF, 0xF, false);
            x0 = fmaxf(x0, __int_as_float(sh));
            xi = __float_as_int(x0);
            sh = __builtin_amdgcn_update_dpp(xi, xi, 0x114, 0xF, 0xF, false);
            x0 = fmaxf(x0, __int_as_float(sh));
            xi = __float_as_int(x0);
            sh = __builtin_amdgcn_update_dpp(xi, xi, 0x118, 0xF, 0xF, false);
            x0 = fmaxf(x0, __int_as_float(sh));
            x0 = fmaxf(x0, __int_as_float(
                     __builtin_amdgcn_ds_swizzle(__float_as_int(x0), 0x401F)));
            x0 = fmaxf(x0, __shfl_xor(x0, 32));
        }
        unsigned g = (unsigned)__builtin_amdgcn_readlane(__float_as_int(x0), 15);
        // ---- index recovery: first (lane, slot) with bits(dmin)==g ----
        int loc = 8;
        if (__float_as_uint(dmin[3].y) == g) loc = 7;
        if (__float_as_uint(dmin[3].x) == g) loc = 6;
        if (__float_as_uint(dmin[2].y) == g) loc = 5;
        if (__float_as_uint(dmin[2].x) == g) loc = 4;
        if (__float_as_uint(dmin[1].y) == g) loc = 3;
        if (__float_as_uint(dmin[1].x) == g) loc = 2;
        if (__float_as_uint(dmin[0].y) == g) loc = 1;
        if (__float_as_uint(dmin[0].x) == g) loc = 0;
        unsigned long long bal = __ballot(loc < 8);
        int l = __ffsll((long long)bal) - 1;
        int widx_w = __shfl(base + loc, l);
        // ---- cross-wave: packed u64 atomic max (dist bits | ~idx) ----
        if (lane == 0) {
            unsigned long long pk =
                ((unsigned long long)g << 32) | (unsigned long long)(unsigned)(~widx_w);
            atomicMax(&slot[m & 3], pk);
        }
        if (tid == 0) slot[(m + 2) & 3] = 0ull;   // 2 barriers from any reader
        __syncthreads();
        unsigned long long w = slot[m & 3];
        int widx = __builtin_amdgcn_readfirstlane(~(unsigned)(w & 0xffffffffu));
        int wj = widx * 3;
        lx = lp[wj + 0];
        ly = lp[wj + 1];
        lz = lp[wj + 2];
        if (tid == 0) {
            p2out[((size_t)b * MOUT + m) * 3 + 0] = lx;
            p2out[((size_t)b * MOUT + m) * 3 + 1] = ly;
            p2out[((size_t)b * MOUT + m) * 3 + 2] = lz;
        }
    }
}

// ---------------------------------------------------------------------------
// kNN: one wave per query. Distributed sorted top-16 in lanes 0..15,
// ballot-compacted insertion. d2 mirrors reference formula exactly.
// ---------------------------------------------------------------------------
__global__ __launch_bounds__(256) void knn_kernel(const float* __restrict__ p1,
                                                  const float* __restrict__ p2,
                                                  int* __restrict__ nnout) {
    int tid = threadIdx.x;
    int lane = tid & 63, wid = tid >> 6;
    int qid = blockIdx.x * 4 + wid;          // 0..8191
    int b = qid >> 11;
    const float* Pb = p1 + (size_t)b * NPTS * 3;
    const float* q = p2 + (size_t)qid * 3;
    float qx = q[0], qy = q[1], qz = q[2];
    float s2q = __fadd_rn(__fadd_rn(__fmul_rn(qx, qx), __fmul_rn(qy, qy)),
                          __fmul_rn(qz, qz));

    float tval = 3.0e38f;   // distributed sorted list (lanes 0..15)
    int   tidx = -1;
    float tau = 3.0e38f;

    for (int n0 = 0; n0 < NPTS; n0 += 64) {
        int n = n0 + lane;
        const float* pp = Pb + n * 3;
        float px = pp[0], py = pp[1], pz = pp[2];
        float s1n = __fadd_rn(__fadd_rn(__fmul_rn(px, px), __fmul_rn(py, py)),
                              __fmul_rn(pz, pz));
        float dot = __fadd_rn(__fadd_rn(__fmul_rn(qx, px), __fmul_rn(qy, py)),
                              __fmul_rn(qz, pz));
        float d2 = __fsub_rn(__fadd_rn(s2q, s1n), __fmul_rn(2.0f, dot));

        unsigned long long act = __ballot(d2 < tau);
        while (act) {
            int l = __ffsll(act) - 1;
            float dd = __shfl(d2, l);
            int   nn_ = __shfl(n, l);
            unsigned long long mle = __ballot(lane < 16 && tval <= dd);
            int pos = __popcll(mle);                 // stable insert position
            float sv = __shfl_up(tval, 1);
            int   si = __shfl_up(tidx, 1);
            if (lane < 16) {
                if (lane == pos)      { tval = dd; tidx = nn_; }
                else if (lane > pos)  { tval = sv; tidx = si; }
            }
            tau = __shfl(tval, 15);
            act &= (act - 1);
            act &= __ballot(d2 < tau);
        }
    }
    if (lane < 16) nnout[(size_t)qid * KNN + lane] = tidx;
}

// ---------------------------------------------------------------------------
// Fused gather + conv1(BN-folded)+ReLU + conv2(BN-folded)+ReLU + max over K.
// ---------------------------------------------------------------------------
template <int XT>
__global__ __launch_bounds__(256) void conv_kernel(const float* __restrict__ p1,
                                                   const float* __restrict__ p2,
                                                   const float* __restrict__ xsrc,
                                                   const int* __restrict__ nn,
                                                   const float* __restrict__ wbuf,
                                                   float* __restrict__ y) {
    const float* w1s = wbuf;
    const float* c1s = wbuf + 2240;
    const float* w2s = wbuf + 2304;
    const float* c2s = wbuf + 6400;
    int tid = threadIdx.x;
    int lane = tid & 63, wid = tid >> 6;
    int qq = lane >> 4, k = lane & 15;
    int qid = (blockIdx.x * 4 + wid) * 4 + qq;   // 0..8191
    int b = qid >> 11, m = qid & 2047;
    int nk = nn[(size_t)qid * KNN + k];

    const float* qp = p2 + (size_t)qid * 3;
    const float* np = p1 + ((size_t)b * NPTS + nk) * 3;
    float h[35];
    h[0] = np[0] - qp[0];
    h[1] = np[1] - qp[1];
    h[2] = np[2] - qp[2];
    if (XT) {
        const float4* xr = (const float4*)(xsrc + ((size_t)b * NPTS + nk) * CIN);
#pragma unroll
        for (int q8 = 0; q8 < 8; ++q8) {
            float4 f = xr[q8];
            h[3 + q8 * 4 + 0] = f.x;
            h[3 + q8 * 4 + 1] = f.y;
            h[3 + q8 * 4 + 2] = f.z;
            h[3 + q8 * 4 + 3] = f.w;
        }
    } else {
#pragma unroll
        for (int c = 0; c < CIN; ++c)
            h[3 + c] = xsrc[((size_t)b * CIN + c) * NPTS + nk];
    }

    float acc2[64];
#pragma unroll
    for (int o2 = 0; o2 < 64; ++o2) acc2[o2] = c2s[o2];

    for (int o = 0; o < 64; ++o) {
        float a = c1s[o];
#pragma unroll
        for (int c = 0; c < 35; ++c) a = fmaf(h[c], w1s[o * 35 + c], a);
        a = fmaxf(a, 0.0f);
#pragma unroll
        for (int o2 = 0; o2 < 64; ++o2) acc2[o2] = fmaf(a, w2s[o2 * 64 + o], acc2[o2]);
    }

#pragma unroll
    for (int o2 = 0; o2 < 64; ++o2) {
        float v = fmaxf(acc2[o2], 0.0f);
        v = fmaxf(v, __shfl_xor(v, 8));
        v = fmaxf(v, __shfl_xor(v, 4));
        v = fmaxf(v, __shfl_xor(v, 2));
        v = fmaxf(v, __shfl_xor(v, 1));
        if ((lane & 15) == (o2 & 15))
            y[((size_t)b * COUT + o2) * MOUT + m] = v;
    }
}

// ---------------------------------------------------------------------------
extern "C" void kernel_launch(void* const* d_in, const int* in_sizes, int n_in,
                              void* d_out, int out_size, void* d_ws, size_t ws_size,
                              hipStream_t stream) {
    const float* p1 = (const float*)d_in[0];
    const float* x  = (const float*)d_in[1];
    const float* w1 = (const float*)d_in[2];
    const float* g1 = (const float*)d_in[3];
    const float* b1 = (const float*)d_in[4];
    const float* m1 = (const float*)d_in[5];
    const float* v1 = (const float*)d_in[6];
    const float* w2 = (const float*)d_in[7];
    const float* g2 = (const float*)d_in[8];
    const float* b2 = (const float*)d_in[9];
    const float* m2 = (const float*)d_in[10];
    const float* v2 = (const float*)d_in[11];

    float* p2o = (float*)d_out;                       // (B,M,3)
    float* yo  = p2o + (size_t)NB * MOUT * 3;         // (B,COUT,M)

    char* ws = (char*)d_ws;
    int*   nn   = (int*)ws;                            // 512 KiB
    float* wbuf = (float*)(ws + 512 * 1024);           // 25.9 KiB
    float* xt   = (float*)(ws + 1024 * 1024);          // 4 MiB
    bool use_xt = ws_size >= (size_t)(1024 * 1024) + (size_t)NB * NPTS * CIN * 4;

    setup_kernel<<<1, 64, 0, stream>>>(w1, g1, b1, m1, v1, w2, g2, b2, m2, v2, wbuf);
    if (use_xt)
        transpose_kernel<<<dim3(NPTS / 64, NB), 256, 0, stream>>>(x, xt);
    fps_kernel<<<NB, 1024, 0, stream>>>(p1, p2o);
    knn_kernel<<<(NB * MOUT) / 4, 256, 0, stream>>>(p1, p2o, nn);
    if (use_xt)
        conv_kernel<1><<<(NB * MOUT) / 16, 256, 0, stream>>>(p1, p2o, xt, nn, wbuf, yo);
    else
        conv_kernel<0><<<(NB * MOUT) / 16, 256, 0, stream>>>(p1, p2o, x, nn, wbuf, yo);
}

// Round 6
// 2359.294 us; speedup vs baseline: 1.3737x; 1.0929x over previous
//
#include <hip/hip_runtime.h>
#include <hip/hip_bf16.h>

#define NB 4
#define NPTS 8192
#define CIN 32
#define COUT 64
#define MOUT 2048   // NPTS / STRIDE
#define KNN 16
#define EPSBN 1e-5f

typedef float f32x2 __attribute__((ext_vector_type(2)));

// ---------------------------------------------------------------------------
// Setup: fold BN into conv weights.  w1s[o][c] = w1[o][c]*a1[o], c1[o]=b1-m1*a1
// wbuf layout (floats): [0,2240) w1s | [2240,2304) c1 | [2304,6400) w2s | [6400,6464) c2
// ---------------------------------------------------------------------------
__global__ void setup_kernel(const float* __restrict__ w1, const float* __restrict__ g1,
                             const float* __restrict__ b1, const float* __restrict__ m1,
                             const float* __restrict__ v1, const float* __restrict__ w2,
                             const float* __restrict__ g2, const float* __restrict__ b2,
                             const float* __restrict__ m2, const float* __restrict__ v2,
                             float* __restrict__ wbuf) {
    int o = threadIdx.x;
    if (o >= 64) return;
    float a1 = g1[o] * rsqrtf(v1[o] + EPSBN);
    wbuf[2240 + o] = b1[o] - m1[o] * a1;
    for (int c = 0; c < 35; ++c) wbuf[o * 35 + c] = w1[o * 35 + c] * a1;
    float a2 = g2[o] * rsqrtf(v2[o] + EPSBN);
    wbuf[6400 + o] = b2[o] - m2[o] * a2;
    for (int c = 0; c < 64; ++c) wbuf[2304 + o * 64 + c] = w2[o * 64 + c] * a2;
}

// ---------------------------------------------------------------------------
// Transpose x (B,C,N) -> xt (B,N,C) with LDS tiles (coalesced both sides)
// ---------------------------------------------------------------------------
__global__ __launch_bounds__(256) void transpose_kernel(const float* __restrict__ x,
                                                        float* __restrict__ xt) {
    __shared__ float tile[CIN][65];
    int b = blockIdx.y;
    int n0 = blockIdx.x * 64;
    int tid = threadIdx.x;
#pragma unroll
    for (int r = 0; r < 8; ++r) {
        int i = r * 256 + tid;
        int c = i >> 6, n = i & 63;
        tile[c][n] = x[((size_t)b * CIN + c) * NPTS + n0 + n];
    }
    __syncthreads();
#pragma unroll
    for (int r = 0; r < 8; ++r) {
        int i = r * 256 + tid;
        int n = i >> 5, c = i & 31;
        xt[((size_t)b * NPTS + n0 + n) * CIN + c] = tile[c][n];
    }
}

// ---------------------------------------------------------------------------
// FPS v5: 512 threads/block, 16 pts/thread in registers (8 f32x2 slots,
// pinned), points staged in LDS. Native f32x2 arithmetic under
// fp contract(off): compiler emits v_pk_add/mul/min without the asm-copy
// bloat r5 measured (75% VALU-busy, ~2x hand count). Cross-wave winner via
// parity-double-buffered warr[2][8] + 3-step u64 butterfly (no serialized
// atomics, no slot resets). Exactness: d=(dx*dx+dy*dy)+dz*dz, no contraction;
// argmax = first occurrence of max (descending slot scan -> smallest slot,
// ballot -> smallest lane, u64 pack (val<<32)|~idx -> smallest index
// cross-wave; contiguous index ownership makes lane order = index order).
// Distances >= 0 so bit-equality == float equality.
// ---------------------------------------------------------------------------
#define FPS_PT 16
__global__ __launch_bounds__(512) void fps_kernel(const float* __restrict__ p1,
                                                  float* __restrict__ p2out) {
#pragma clang fp contract(off)
    int b = blockIdx.x;
    int tid = threadIdx.x;
    int lane = tid & 63;
    int wv = tid >> 6;                        // 0..7
    const float* P = p1 + (size_t)b * NPTS * 3;

    __shared__ float lp[NPTS * 3];            // 96 KiB point stage
    __shared__ unsigned long long warr[2][8];

    const float4* P4 = (const float4*)P;
    float4* L4 = (float4*)lp;
#pragma unroll
    for (int r = 0; r < 12; ++r) {
        int i = r * 512 + tid;
        L4[i] = P4[i];
    }
    __syncthreads();

    f32x2 px[8], py[8], pz[8], dmin[8];
    int base = tid * FPS_PT;
#pragma unroll
    for (int s = 0; s < 8; ++s) {
        int j = (base + 2 * s) * 3;
        px[s] = (f32x2){lp[j + 0], lp[j + 3]};
        py[s] = (f32x2){lp[j + 1], lp[j + 4]};
        pz[s] = (f32x2){lp[j + 2], lp[j + 5]};
        dmin[s] = (f32x2){1e10f, 1e10f};
        // pin: opaque producer -> no remat/re-load inside the loop (r5: works)
        asm volatile("" : "+v"(px[s]), "+v"(py[s]), "+v"(pz[s]));
    }

    float lx = lp[0], ly = lp[1], lz = lp[2];
    if (tid == 0) {
        p2out[(size_t)(b * MOUT) * 3 + 0] = lx;
        p2out[(size_t)(b * MOUT) * 3 + 1] = ly;
        p2out[(size_t)(b * MOUT) * 3 + 2] = lz;
    }

    for (int m = 1; m < MOUT; ++m) {
        // ---- phase A: packed distance + dmin update (contract OFF) ----
        f32x2 lxv = {lx, lx}, lyv = {ly, ly}, lzv = {lz, lz};
#pragma unroll
        for (int s = 0; s < 8; ++s) {
            f32x2 dx = px[s] - lxv;
            f32x2 dy = py[s] - lyv;
            f32x2 dz = pz[s] - lzv;
            f32x2 d = (dx * dx + dy * dy) + dz * dz;   // mul/add only, in order
            dmin[s] = __builtin_elementwise_min(dmin[s], d);
        }
        // ---- local max tree: 7 pk_max + 1 scalar ----
        f32x2 t0 = __builtin_elementwise_max(dmin[0], dmin[1]);
        f32x2 t1 = __builtin_elementwise_max(dmin[2], dmin[3]);
        f32x2 t2 = __builtin_elementwise_max(dmin[4], dmin[5]);
        f32x2 t3 = __builtin_elementwise_max(dmin[6], dmin[7]);
        f32x2 u0 = __builtin_elementwise_max(t0, t1);
        f32x2 u1 = __builtin_elementwise_max(t2, t3);
        f32x2 v2m = __builtin_elementwise_max(u0, u1);
        float bv = fmaxf(v2m.x, v2m.y);
        // ---- wave value-max: 4x DPP row_shr + xor16 swizzle + xor32 ----
        float x0 = bv;
        {
            int xi, sh;
            xi = __float_as_int(x0);
            sh = __builtin_amdgcn_update_dpp(xi, xi, 0x111, 0xF, 0xF, false);
            x0 = fmaxf(x0, __int_as_float(sh));
            xi = __float_as_int(x0);
            sh = __builtin_amdgcn_update_dpp(xi, xi, 0x112, 0xF, 0xF, false);
            x0 = fmaxf(x0, __int_as_float(sh));
            xi = __float_as_int(x0);
            sh = __builtin_amdgcn_update_dpp(xi, xi, 0x114, 0xF, 0xF, false);
            x0 = fmaxf(x0, __int_as_float(sh));
            xi = __float_as_int(x0);
            sh = __builtin_amdgcn_update_dpp(xi, xi, 0x118, 0xF, 0xF, false);
            x0 = fmaxf(x0, __int_as_float(sh));
            x0 = fmaxf(x0, __int_as_float(
                     __builtin_amdgcn_ds_swizzle(__float_as_int(x0), 0x401F)));
            x0 = fmaxf(x0, __shfl_xor(x0, 32));
        }
        unsigned g = (unsigned)__builtin_amdgcn_readlane(__float_as_int(x0), 15);
        // ---- index recovery: first (lane, slot) with bits(dmin)==g ----
        int loc = 16;
        if (__float_as_uint(dmin[7].y) == g) loc = 15;
        if (__float_as_uint(dmin[7].x) == g) loc = 14;
        if (__float_as_uint(dmin[6].y) == g) loc = 13;
        if (__float_as_uint(dmin[6].x) == g) loc = 12;
        if (__float_as_uint(dmin[5].y) == g) loc = 11;
        if (__float_as_uint(dmin[5].x) == g) loc = 10;
        if (__float_as_uint(dmin[4].y) == g) loc = 9;
        if (__float_as_uint(dmin[4].x) == g) loc = 8;
        if (__float_as_uint(dmin[3].y) == g) loc = 7;
        if (__float_as_uint(dmin[3].x) == g) loc = 6;
        if (__float_as_uint(dmin[2].y) == g) loc = 5;
        if (__float_as_uint(dmin[2].x) == g) loc = 4;
        if (__float_as_uint(dmin[1].y) == g) loc = 3;
        if (__float_as_uint(dmin[1].x) == g) loc = 2;
        if (__float_as_uint(dmin[0].y) == g) loc = 1;
        if (__float_as_uint(dmin[0].x) == g) loc = 0;
        unsigned long long bal = __ballot(loc < 16);
        int l = __ffsll((long long)bal) - 1;
        int widx_w = __shfl(base + loc, l);
        // ---- cross-wave: per-wave slot write + butterfly u64 max ----
        int par = m & 1;
        if (lane == 0) {
            unsigned long long pk =
                ((unsigned long long)g << 32) | (unsigned long long)(unsigned)(~widx_w);
            warr[par][wv] = pk;
        }
        __syncthreads();
        unsigned long long e = warr[par][lane & 7];
#pragma unroll
        for (int off = 1; off <= 4; off <<= 1) {
            unsigned long long o = __shfl_xor(e, off);
            if (o > e) e = o;
        }
        int widx = ~(unsigned)(e & 0xffffffffull);
        int wj = widx * 3;
        lx = lp[wj + 0];
        ly = lp[wj + 1];
        lz = lp[wj + 2];
        if (tid == 0) {
            p2out[((size_t)b * MOUT + m) * 3 + 0] = lx;
            p2out[((size_t)b * MOUT + m) * 3 + 1] = ly;
            p2out[((size_t)b * MOUT + m) * 3 + 2] = lz;
        }
    }
}

// ---------------------------------------------------------------------------
// kNN: one wave per query. Distributed sorted top-16 in lanes 0..15,
// ballot-compacted insertion. d2 mirrors reference formula exactly.
// ---------------------------------------------------------------------------
__global__ __launch_bounds__(256) void knn_kernel(const float* __restrict__ p1,
                                                  const float* __restrict__ p2,
                                                  int* __restrict__ nnout) {
    int tid = threadIdx.x;
    int lane = tid & 63, wid = tid >> 6;
    int qid = blockIdx.x * 4 + wid;          // 0..8191
    int b = qid >> 11;
    const float* Pb = p1 + (size_t)b * NPTS * 3;
    const float* q = p2 + (size_t)qid * 3;
    float qx = q[0], qy = q[1], qz = q[2];
    float s2q = __fadd_rn(__fadd_rn(__fmul_rn(qx, qx), __fmul_rn(qy, qy)),
                          __fmul_rn(qz, qz));

    float tval = 3.0e38f;   // distributed sorted list (lanes 0..15)
    int   tidx = -1;
    float tau = 3.0e38f;

    for (int n0 = 0; n0 < NPTS; n0 += 64) {
        int n = n0 + lane;
        const float* pp = Pb + n * 3;
        float px = pp[0], py = pp[1], pz = pp[2];
        float s1n = __fadd_rn(__fadd_rn(__fmul_rn(px, px), __fmul_rn(py, py)),
                              __fmul_rn(pz, pz));
        float dot = __fadd_rn(__fadd_rn(__fmul_rn(qx, px), __fmul_rn(qy, py)),
                              __fmul_rn(qz, pz));
        float d2 = __fsub_rn(__fadd_rn(s2q, s1n), __fmul_rn(2.0f, dot));

        unsigned long long act = __ballot(d2 < tau);
        while (act) {
            int l = __ffsll(act) - 1;
            float dd = __shfl(d2, l);
            int   nn_ = __shfl(n, l);
            unsigned long long mle = __ballot(lane < 16 && tval <= dd);
            int pos = __popcll(mle);                 // stable insert position
            float sv = __shfl_up(tval, 1);
            int   si = __shfl_up(tidx, 1);
            if (lane < 16) {
                if (lane == pos)      { tval = dd; tidx = nn_; }
                else if (lane > pos)  { tval = sv; tidx = si; }
            }
            tau = __shfl(tval, 15);
            act &= (act - 1);
            act &= __ballot(d2 < tau);
        }
    }
    if (lane < 16) nnout[(size_t)qid * KNN + lane] = tidx;
}

// ---------------------------------------------------------------------------
// Fused gather + conv1(BN-folded)+ReLU + conv2(BN-folded)+ReLU + max over K.
// ---------------------------------------------------------------------------
template <int XT>
__global__ __launch_bounds__(256) void conv_kernel(const float* __restrict__ p1,
                                                   const float* __restrict__ p2,
                                                   const float* __restrict__ xsrc,
                                                   const int* __restrict__ nn,
                                                   const float* __restrict__ wbuf,
                                                   float* __restrict__ y) {
    const float* w1s = wbuf;
    const float* c1s = wbuf + 2240;
    const float* w2s = wbuf + 2304;
    const float* c2s = wbuf + 6400;
    int tid = threadIdx.x;
    int lane = tid & 63, wid = tid >> 6;
    int qq = lane >> 4, k = lane & 15;
    int qid = (blockIdx.x * 4 + wid) * 4 + qq;   // 0..8191
    int b = qid >> 11, m = qid & 2047;
    int nk = nn[(size_t)qid * KNN + k];

    const float* qp = p2 + (size_t)qid * 3;
    const float* np = p1 + ((size_t)b * NPTS + nk) * 3;
    float h[35];
    h[0] = np[0] - qp[0];
    h[1] = np[1] - qp[1];
    h[2] = np[2] - qp[2];
    if (XT) {
        const float4* xr = (const float4*)(xsrc + ((size_t)b * NPTS + nk) * CIN);
#pragma unroll
        for (int q8 = 0; q8 < 8; ++q8) {
            float4 f = xr[q8];
            h[3 + q8 * 4 + 0] = f.x;
            h[3 + q8 * 4 + 1] = f.y;
            h[3 + q8 * 4 + 2] = f.z;
            h[3 + q8 * 4 + 3] = f.w;
        }
    } else {
#pragma unroll
        for (int c = 0; c < CIN; ++c)
            h[3 + c] = xsrc[((size_t)b * CIN + c) * NPTS + nk];
    }

    float acc2[64];
#pragma unroll
    for (int o2 = 0; o2 < 64; ++o2) acc2[o2] = c2s[o2];

    for (int o = 0; o < 64; ++o) {
        float a = c1s[o];
#pragma unroll
        for (int c = 0; c < 35; ++c) a = fmaf(h[c], w1s[o * 35 + c], a);
        a = fmaxf(a, 0.0f);
#pragma unroll
        for (int o2 = 0; o2 < 64; ++o2) acc2[o2] = fmaf(a, w2s[o2 * 64 + o], acc2[o2]);
    }

#pragma unroll
    for (int o2 = 0; o2 < 64; ++o2) {
        float v = fmaxf(acc2[o2], 0.0f);
        v = fmaxf(v, __shfl_xor(v, 8));
        v = fmaxf(v, __shfl_xor(v, 4));
        v = fmaxf(v, __shfl_xor(v, 2));
        v = fmaxf(v, __shfl_xor(v, 1));
        if ((lane & 15) == (o2 & 15))
            y[((size_t)b * COUT + o2) * MOUT + m] = v;
    }
}

// ---------------------------------------------------------------------------
extern "C" void kernel_launch(void* const* d_in, const int* in_sizes, int n_in,
                              void* d_out, int out_size, void* d_ws, size_t ws_size,
                              hipStream_t stream) {
    const float* p1 = (const float*)d_in[0];
    const float* x  = (const float*)d_in[1];
    const float* w1 = (const float*)d_in[2];
    const float* g1 = (const float*)d_in[3];
    const float* b1 = (const float*)d_in[4];
    const float* m1 = (const float*)d_in[5];
    const float* v1 = (const float*)d_in[6];
    const float* w2 = (const float*)d_in[7];
    const float* g2 = (const float*)d_in[8];
    const float* b2 = (const float*)d_in[9];
    const float* m2 = (const float*)d_in[10];
    const float* v2 = (const float*)d_in[11];

    float* p2o = (float*)d_out;                       // (B,M,3)
    float* yo  = p2o + (size_t)NB * MOUT * 3;         // (B,COUT,M)

    char* ws = (char*)d_ws;
    int*   nn   = (int*)ws;                            // 512 KiB
    float* wbuf = (float*)(ws + 512 * 1024);           // 25.9 KiB
    float* xt   = (float*)(ws + 1024 * 1024);          // 4 MiB
    bool use_xt = ws_size >= (size_t)(1024 * 1024) + (size_t)NB * NPTS * CIN * 4;

    setup_kernel<<<1, 64, 0, stream>>>(w1, g1, b1, m1, v1, w2, g2, b2, m2, v2, wbuf);
    if (use_xt)
        transpose_kernel<<<dim3(NPTS / 64, NB), 256, 0, stream>>>(x, xt);
    fps_kernel<<<NB, 512, 0, stream>>>(p1, p2o);
    knn_kernel<<<(NB * MOUT) / 4, 256, 0, stream>>>(p1, p2o, nn);
    if (use_xt)
        conv_kernel<1><<<(NB * MOUT) / 16, 256, 0, stream>>>(p1, p2o, xt, nn, wbuf, yo);
    else
        conv_kernel<0><<<(NB * MOUT) / 16, 256, 0, stream>>>(p1, p2o, x, nn, wbuf, yo);
}